// Round 13
// baseline (228.180 us; speedup 1.0000x reference)
//
#include <hip/hip_runtime.h>

typedef unsigned short u16;
typedef __attribute__((ext_vector_type(4)))  float  f32x4;
typedef __attribute__((ext_vector_type(8)))  short  s16x8;
typedef __attribute__((ext_vector_type(8)))  unsigned short u16x8;
typedef __attribute__((ext_vector_type(4)))  unsigned short u16x4;
typedef __attribute__((ext_vector_type(4)))  float  f4;

#define AS1(p) ((const __attribute__((address_space(1))) void*)(p))
#define AS3(p) ((__attribute__((address_space(3))) void*)(p))

__device__ __forceinline__ float bf2f(u16 u) {
    unsigned v = ((unsigned)u) << 16;
    return __builtin_bit_cast(float, v);
}
__device__ __forceinline__ u16 f2bf(float f) {
    unsigned u = __builtin_bit_cast(unsigned, f);
    unsigned r = u + 0x7FFFu + ((u >> 16) & 1u);
    return (u16)(r >> 16);
}

#define SB __builtin_amdgcn_sched_barrier(0)
#define GATE0 do { asm volatile("s_waitcnt vmcnt(0)" ::: "memory"); SB; } while (0)

// ---------------- prep: casts (blocks 0..21445) + weight transposes (21446..36805) ----------------
struct PrepJobs {
    const float* cin[4]; u16* cout[4]; long cb[3];
    const float* tin[8]; u16* tout[8]; int tK[8];
};
__global__ __launch_bounds__(256) void prep_kernel(PrepJobs J) {
    const int bid = blockIdx.x;
    const int t = threadIdx.x;
    if (bid < 21446) {               // cast path (total4 = 5490176 = 21446*256 exactly)
        long i = (long)bid * 256 + t;
        int j = (i >= J.cb[0]) + (i >= J.cb[1]) + (i >= J.cb[2]);
        long k = i - (j ? J.cb[j - 1] : 0);
        f4 v = ((const f4*)J.cin[j])[k];
        u16x4 o;
        o[0] = f2bf(v.x); o[1] = f2bf(v.y); o[2] = f2bf(v.z); o[3] = f2bf(v.w);
        ((u16x4*)J.cout[j])[k] = o;
        return;
    }
    // transpose path
    int u = bid - 21446;
    int j = (u >= 1600) + (u >= 4160) + (u >= 6720) + (u >= 7680)
          + (u >= 8640) + (u >= 11200) + (u >= 13760);
    const int cumprev[8] = {0, 1600, 4160, 6720, 7680, 8640, 11200, 13760};
    int rem = u - cumprev[j];
    const float* in = J.tin[j];
    u16* out = J.tout[j];
    const int K = J.tK[j];
    const int nb = (rem % 40) * 32;
    const int kb = (rem / 40) * 32;
    __shared__ float tile[32][33];
    const int tx = t & 31, ty = t >> 5;
#pragma unroll
    for (int r = 0; r < 32; r += 8)
        tile[ty + r][tx] = in[(size_t)(kb + ty + r) * 1280 + nb + tx];
    __syncthreads();
#pragma unroll
    for (int r = 0; r < 32; r += 8)
        out[(size_t)(nb + ty + r) * K + kb + tx] = f2bf(tile[tx][ty + r]);
}

// ================= standalone merged 2-phase 128x160 GEMM (out-projection) =================
template <int EPI>   // 0 = bf16 store; 2 = f32 + bias[col] + bf16 resid
__global__ __launch_bounds__(256, 2) void gemm_8p(
    const u16* __restrict__ A, const u16* __restrict__ Bt, void* __restrict__ outp,
    const float* __restrict__ bias, const u16* __restrict__ resid)
{
    const int K = 1280, N = 1280;
    __shared__ u16 lsA[2][128 * 64];
    __shared__ u16 lsB[2][160 * 64];

    const int bid = blockIdx.x;
    const int swz = (bid & 7) * 128 + (bid >> 3);
    const int m0 = (swz >> 3) * 128;
    const int n0 = (swz & 7) * 160;

    const int t = threadIdx.x;
    const int lane = t & 63, wid = t >> 6;
    const int wm = wid >> 1, wn = wid & 1;
    const int fr = lane & 15, hi = lane >> 4;
    const int fr7 = fr & 7;

    const int srow = t >> 3;
    const int sslot = (t & 7) ^ (srow & 7);
    const u16* gA = A  + (size_t)(m0 + srow) * K + sslot * 8;
    const u16* gB = Bt + (size_t)(n0 + srow) * K + sslot * 8;
    const size_t cK = (size_t)32 * K;

#define STGA(BUF, CC, KO) __builtin_amdgcn_global_load_lds(AS1(gA + (CC) * cK + (KO)), \
        AS3((char*)lsA + (BUF) * 16384 + (CC) * 4096 + t * 16), 16, 0, 0)
#define STGB(BUF, CC, KO) __builtin_amdgcn_global_load_lds(AS1(gB + (CC) * cK + (KO)), \
        AS3((char*)lsB + (BUF) * 20480 + (CC) * 4096 + t * 16), 16, 0, 0)
#define STG9(BUF, KO) do { \
    STGB(BUF, 0, KO); STGB(BUF, 1, KO); STGB(BUF, 2, KO); STGB(BUF, 3, KO); STGB(BUF, 4, KO); \
    STGA(BUF, 0, KO); STGA(BUF, 1, KO); STGA(BUF, 2, KO); STGA(BUF, 3, KO); \
} while (0)

    const char* lA0 = (const char*)lsA + (size_t)(wm * 64 + fr) * 128 + (((0 + hi) ^ fr7) << 4);
    const char* lA1 = (const char*)lsA + (size_t)(wm * 64 + fr) * 128 + (((4 + hi) ^ fr7) << 4);
    const char* lB0 = (const char*)lsB + (size_t)(wn * 80 + fr) * 128 + (((0 + hi) ^ fr7) << 4);
    const char* lB1 = (const char*)lsB + (size_t)(wn * 80 + fr) * 128 + (((4 + hi) ^ fr7) << 4);

    f32x4 acc[4][5];
#pragma unroll
    for (int i = 0; i < 4; i++)
#pragma unroll
        for (int j = 0; j < 5; j++)
            acc[i][j] = (f32x4){0.f, 0.f, 0.f, 0.f};

    s16x8 af[4], bfv[5];

#define DSRD2(BUF, KS) do { \
    _Pragma("unroll") for (int mi = 0; mi < 4; mi++) \
        af[mi] = *(const s16x8*)(((KS) ? lA1 : lA0) + (BUF) * 16384 + mi * 2048); \
    _Pragma("unroll") for (int nf = 0; nf < 5; nf++) \
        bfv[nf] = *(const s16x8*)(((KS) ? lB1 : lB0) + (BUF) * 20480 + nf * 2048); \
} while (0)
#define MM2 do { \
    _Pragma("unroll") for (int mi = 0; mi < 4; mi++) \
        _Pragma("unroll") for (int nf = 0; nf < 5; nf++) \
            acc[mi][nf] = __builtin_amdgcn_mfma_f32_16x16x32_bf16( \
                af[mi], bfv[nf], acc[mi][nf], 0, 0, 0); \
} while (0)
#define PHA(BUF, DOSTG, KO) do { \
    DSRD2(BUF, 0); \
    if (DOSTG) STG9((BUF) ^ 1, KO); \
    SB; __builtin_amdgcn_s_barrier(); SB; \
    asm volatile("s_waitcnt lgkmcnt(0)" ::: "memory"); SB; \
    __builtin_amdgcn_s_setprio(1); MM2; __builtin_amdgcn_s_setprio(0); SB; \
    __builtin_amdgcn_s_barrier(); SB; \
} while (0)
#define PHB(BUF, DOGATE) do { \
    DSRD2(BUF, 1); \
    SB; __builtin_amdgcn_s_barrier(); SB; \
    asm volatile("s_waitcnt lgkmcnt(0)" ::: "memory"); SB; \
    __builtin_amdgcn_s_setprio(1); MM2; __builtin_amdgcn_s_setprio(0); SB; \
    if (DOGATE) { GATE0; } \
    __builtin_amdgcn_s_barrier(); SB; \
} while (0)

    STG9(0, 0);
    GATE0;
    __builtin_amdgcn_s_barrier();
    SB;

    for (int i = 0; i < 9; i++) {
        const size_t k1 = (size_t)(2 * i + 1) * 64, k2 = k1 + 64;
        PHA(0, 1, k1); PHB(0, 1);
        PHA(1, 1, k2); PHB(1, 1);
    }
    PHA(0, 1, (size_t)19 * 64); PHB(0, 1);
    PHA(1, 0, 0);               PHB(1, 0);

#pragma unroll
    for (int mf = 0; mf < 4; mf++) {
#pragma unroll
        for (int nf = 0; nf < 5; nf++) {
#pragma unroll
            for (int j = 0; j < 4; j++) {
                int row = m0 + wm * 64 + mf * 16 + hi * 4 + j;
                int col = n0 + wn * 80 + nf * 16 + fr;
                float v = acc[mf][nf][j];
                if constexpr (EPI == 0) {
                    ((u16*)outp)[(size_t)row * N + col] = f2bf(v);
                } else {
                    ((float*)outp)[(size_t)row * N + col] =
                        v + bias[col] + bf2f(resid[(size_t)row * N + col]);
                }
            }
        }
    }
#undef STGA
#undef STGB
#undef STG9
#undef DSRD2
#undef MM2
#undef PHA
#undef PHB
}

// ================= fused launch: KV projections -> images (blocks 0..119) + q-proj (120..1143) =================
struct FKV {
    const u16* A[6]; const u16* Bt[6];
    int K[6], M[6], L[6], base[6];
    u16 *Kimg, *Vimg;
};
__global__ __launch_bounds__(256, 2) void gemm_fused(
    const u16* __restrict__ Aq, const u16* __restrict__ Bq, u16* __restrict__ outq, FKV J)
{
    __shared__ char smem[73728];
    const int t = threadIdx.x;
    const int lane = t & 63, wid = t >> 6;
    const int fr = lane & 15, hi = lane >> 4;
    const int fr7 = fr & 7;

    if (blockIdx.x >= 120) {
        // ---------------- q projection path ----------------
        const int K = 1280;
        const int bid = blockIdx.x - 120;
        const int swz = (bid & 7) * 128 + (bid >> 3);
        const int m0 = (swz >> 3) * 128;
        const int n0 = (swz & 7) * 160;
        const int wm = wid >> 1, wn = wid & 1;
        const int srow = t >> 3;
        const int sslot = (t & 7) ^ (srow & 7);
        const u16* gA = Aq + (size_t)(m0 + srow) * K + sslot * 8;
        const u16* gB = Bq + (size_t)(n0 + srow) * K + sslot * 8;
        const size_t cK = (size_t)32 * K;

#define QSTGA(BUF, CC, KO) __builtin_amdgcn_global_load_lds(AS1(gA + (CC) * cK + (KO)), \
        AS3(smem + (BUF) * 16384 + (CC) * 4096 + t * 16), 16, 0, 0)
#define QSTGB(BUF, CC, KO) __builtin_amdgcn_global_load_lds(AS1(gB + (CC) * cK + (KO)), \
        AS3(smem + 32768 + (BUF) * 20480 + (CC) * 4096 + t * 16), 16, 0, 0)
#define QSTG9(BUF, KO) do { \
    QSTGB(BUF, 0, KO); QSTGB(BUF, 1, KO); QSTGB(BUF, 2, KO); QSTGB(BUF, 3, KO); QSTGB(BUF, 4, KO); \
    QSTGA(BUF, 0, KO); QSTGA(BUF, 1, KO); QSTGA(BUF, 2, KO); QSTGA(BUF, 3, KO); \
} while (0)

        const char* lA0 = smem + (size_t)(wm * 64 + fr) * 128 + (((0 + hi) ^ fr7) << 4);
        const char* lA1 = smem + (size_t)(wm * 64 + fr) * 128 + (((4 + hi) ^ fr7) << 4);
        const char* lB0 = smem + 32768 + (size_t)(wn * 80 + fr) * 128 + (((0 + hi) ^ fr7) << 4);
        const char* lB1 = smem + 32768 + (size_t)(wn * 80 + fr) * 128 + (((4 + hi) ^ fr7) << 4);

        f32x4 acc[4][5];
#pragma unroll
        for (int i = 0; i < 4; i++)
#pragma unroll
            for (int j = 0; j < 5; j++)
                acc[i][j] = (f32x4){0.f, 0.f, 0.f, 0.f};

        s16x8 af[4], bfv[5];

#define QDSRD2(BUF, KS) do { \
    _Pragma("unroll") for (int mi = 0; mi < 4; mi++) \
        af[mi] = *(const s16x8*)(((KS) ? lA1 : lA0) + (BUF) * 16384 + mi * 2048); \
    _Pragma("unroll") for (int nf = 0; nf < 5; nf++) \
        bfv[nf] = *(const s16x8*)(((KS) ? lB1 : lB0) + (BUF) * 20480 + nf * 2048); \
} while (0)
#define QMM2 do { \
    _Pragma("unroll") for (int mi = 0; mi < 4; mi++) \
        _Pragma("unroll") for (int nf = 0; nf < 5; nf++) \
            acc[mi][nf] = __builtin_amdgcn_mfma_f32_16x16x32_bf16( \
                af[mi], bfv[nf], acc[mi][nf], 0, 0, 0); \
} while (0)
#define QPHA(BUF, DOSTG, KO) do { \
    QDSRD2(BUF, 0); \
    if (DOSTG) QSTG9((BUF) ^ 1, KO); \
    SB; __builtin_amdgcn_s_barrier(); SB; \
    asm volatile("s_waitcnt lgkmcnt(0)" ::: "memory"); SB; \
    __builtin_amdgcn_s_setprio(1); QMM2; __builtin_amdgcn_s_setprio(0); SB; \
    __builtin_amdgcn_s_barrier(); SB; \
} while (0)
#define QPHB(BUF, DOGATE) do { \
    QDSRD2(BUF, 1); \
    SB; __builtin_amdgcn_s_barrier(); SB; \
    asm volatile("s_waitcnt lgkmcnt(0)" ::: "memory"); SB; \
    __builtin_amdgcn_s_setprio(1); QMM2; __builtin_amdgcn_s_setprio(0); SB; \
    if (DOGATE) { GATE0; } \
    __builtin_amdgcn_s_barrier(); SB; \
} while (0)

        QSTG9(0, 0);
        GATE0;
        __builtin_amdgcn_s_barrier();
        SB;

        for (int i = 0; i < 9; i++) {
            const size_t k1 = (size_t)(2 * i + 1) * 64, k2 = k1 + 64;
            QPHA(0, 1, k1); QPHB(0, 1);
            QPHA(1, 1, k2); QPHB(1, 1);
        }
        QPHA(0, 1, (size_t)19 * 64); QPHB(0, 1);
        QPHA(1, 0, 0);               QPHB(1, 0);

#pragma unroll
        for (int mf = 0; mf < 4; mf++) {
#pragma unroll
            for (int nf = 0; nf < 5; nf++) {
#pragma unroll
                for (int j = 0; j < 4; j++) {
                    int row = m0 + wm * 64 + mf * 16 + hi * 4 + j;
                    int col = n0 + wn * 80 + nf * 16 + fr;
                    outq[(size_t)row * 1280 + col] = f2bf(acc[mf][nf][j]);
                }
            }
        }
#undef QSTGA
#undef QSTGB
#undef QSTG9
#undef QDSRD2
#undef QMM2
#undef QPHA
#undef QPHB
        return;
    }

    // ---------------- KV projection path (blocks 0..119) ----------------
    const int kvq = blockIdx.x;
    const int pn = kvq % 10;
    const int rem = kvq / 10;
    int j, bx;
    if (rem < 6)      { j = rem / 3;            bx = rem % 3; }
    else if (rem < 8) { j = rem - 4;            bx = 0; }
    else              { j = 4 + ((rem - 8) >> 1); bx = (rem - 8) & 1; }

    const u16* A  = J.A[j];
    const u16* Bt = J.Bt[j];
    const int K = J.K[j], Mj = J.M[j], Lj = J.L[j], basej = J.base[j];
    const int m0 = bx * 128, n0 = pn * 128;
    const int wr = wid >> 1, wc = wid & 1;
    const int fq = hi;

    f32x4 acc[4][4];
#pragma unroll
    for (int i = 0; i < 4; i++)
#pragma unroll
        for (int jj = 0; jj < 4; jj++)
            acc[i][jj] = (f32x4){0.f, 0.f, 0.f, 0.f};

    const int arow = t >> 3;
    const int aslot = (t & 7) ^ (arow & 7);
    const u16* gA = A  + (size_t)(m0 + arow) * K + aslot * 8;
    const u16* gB = Bt + (size_t)(n0 + arow) * K + aslot * 8;
    const size_t cK = (size_t)32 * K;

#define KSTAGE(buf, k0) do { \
    _Pragma("unroll") for (int c = 0; c < 4; c++) { \
        __builtin_amdgcn_global_load_lds(AS1(gA + c * cK + (k0)), AS3(smem + (buf) * 16384 + c * 4096 + t * 16), 16, 0, 0); \
        __builtin_amdgcn_global_load_lds(AS1(gB + c * cK + (k0)), AS3(smem + 32768 + (buf) * 16384 + c * 4096 + t * 16), 16, 0, 0); \
    } \
} while (0)

    const char* lA0 = smem + (size_t)(wr * 64 + fr) * 128 + (((0 + fq) ^ fr7) << 4);
    const char* lA1 = smem + (size_t)(wr * 64 + fr) * 128 + (((4 + fq) ^ fr7) << 4);
    const char* lB0 = smem + 32768 + (size_t)(wc * 64 + fr) * 128 + (((0 + fq) ^ fr7) << 4);
    const char* lB1 = smem + 32768 + (size_t)(wc * 64 + fr) * 128 + (((4 + fq) ^ fr7) << 4);

    KSTAGE(0, 0);
    __syncthreads();

    int cur = 0;
    for (int k0 = 0; k0 < K; k0 += 64) {
        if (k0 + 64 < K) KSTAGE(cur ^ 1, k0 + 64);

#pragma unroll
        for (int ks = 0; ks < 2; ks++) {
            s16x8 af[4], bfr[4];
#pragma unroll
            for (int i = 0; i < 4; i++) {
                af[i]  = *(const s16x8*)((ks ? lA1 : lA0) + cur * 16384 + i * 2048);
                bfr[i] = *(const s16x8*)((ks ? lB1 : lB0) + cur * 16384 + i * 2048);
            }
#pragma unroll
            for (int mi = 0; mi < 4; mi++)
#pragma unroll
                for (int ni = 0; ni < 4; ni++)
                    acc[mi][ni] = __builtin_amdgcn_mfma_f32_16x16x32_bf16(af[mi], bfr[ni], acc[mi][ni], 0, 0, 0);
        }

        __syncthreads();
        cur ^= 1;
    }
#undef KSTAGE

    const bool isV = (j & 1) != 0;
    u16* img = isV ? J.Vimg : J.Kimg;
    const float scl = isV ? 1.0f : 0.125f;
#pragma unroll
    for (int mi = 0; mi < 4; mi++) {
#pragma unroll
        for (int ni = 0; ni < 4; ni++) {
#pragma unroll
            for (int jj = 0; jj < 4; jj++) {
                int row = m0 + wr * 64 + mi * 16 + fq * 4 + jj;
                if (row < Mj) {
                    int col = n0 + wc * 64 + ni * 16 + fr;
                    int b = row / Lj, kl = row - b * Lj, kg = basej + kl;
                    int h = col >> 6, d = col & 63;
                    size_t bhoff = (size_t)(b * 20 + h) * 16384;
                    int off = isV ? (((d * 256 + (kg >> 3) * 16) ^ ((d & 7) << 4)) + (kg & 7) * 2)
                                  : (((kg * 128 + (d >> 3) * 16) ^ ((kg & 7) << 4)) + (d & 7) * 2);
                    *(u16*)((char*)img + bhoff + off) = f2bf(acc[mi][ni][jj] * scl);
                }
            }
        }
    }
}

// ---------------- MFMA attention: direct global K/V fragment reads (L2-resident images) ----------------
// R13: images (16KB per bh, read by 32 blocks) are L2-resident -> LDS staging was
// pure overhead (Common-mistake #7 / m169). K/V fragments read straight from global
// at the same swizzled offsets (images laid out so linear-copy preserves offsets).
// LDS 48K -> 32K (Q 16K + P overlay 32K) => 3 -> 5 blocks/CU, 2 generations.
// T5 setprio around MFMA clusters (attn-positive regime, m191).
__global__ __launch_bounds__(256) void attn_mfma(
    const u16* __restrict__ q, const u16* __restrict__ Kimg,
    const u16* __restrict__ Vimg, u16* __restrict__ out)
{
    __shared__ char sm[32768];
    char* Qb = sm;

    const int t = threadIdx.x;
    const int lane = t & 63, wid = t >> 6;
    const int lo = lane & 15, hi = lane >> 4;
    const int s0 = blockIdx.x * 128;
    const int bh = blockIdx.y;
    const int b = bh / 20, h = bh - b * 20;
    const size_t rs0 = (size_t)b * 4096 + s0;

    const char* gk = (const char*)(Kimg + (size_t)bh * 8192);
    const char* gv = (const char*)(Vimg + (size_t)bh * 8192);

    // stage Q tile (reg route, swizzled)
#pragma unroll
    for (int i = 0; i < 4; i++) {
        int ch = t + i * 256;
        int r = ch >> 3, cs = ch & 7;
        u16x8 v = *(const u16x8*)(q + (rs0 + r) * 1280 + h * 64 + cs * 8);
        *(u16x8*)(Qb + ((r * 128 + cs * 16) ^ ((r & 7) << 4))) = v;
    }
    __syncthreads();

    // QK^T: wave wid owns q rows [wid*32, wid*32+32); K fragments direct from global
    const int m0r = wid * 32;
    s16x8 qf[2][2];
#pragma unroll
    for (int m = 0; m < 2; m++)
#pragma unroll
        for (int kf = 0; kf < 2; kf++) {
            int r = m0r + m * 16 + lo;
            qf[m][kf] = *(const s16x8*)(Qb + ((r * 128 + (kf * 4 + hi) * 16) ^ ((r & 7) << 4)));
        }
    f32x4 sc[2][8];
#pragma unroll
    for (int m = 0; m < 2; m++)
#pragma unroll
        for (int n = 0; n < 8; n++)
            sc[m][n] = (f32x4){0.f, 0.f, 0.f, 0.f};
    __builtin_amdgcn_s_setprio(1);
#pragma unroll
    for (int kf = 0; kf < 2; kf++)
#pragma unroll
        for (int n = 0; n < 8; n++) {
            int r = n * 16 + lo;
            s16x8 kf8 = *(const s16x8*)(gk + ((r * 128 + (kf * 4 + hi) * 16) ^ ((r & 7) << 4)));
#pragma unroll
            for (int m = 0; m < 2; m++)
                sc[m][n] = __builtin_amdgcn_mfma_f32_16x16x32_bf16(qf[m][kf], kf8, sc[m][n], 0, 0, 0);
        }
    __builtin_amdgcn_s_setprio(0);
    __syncthreads();   // Q LDS reads done; region becomes P

    // softmax (both branches) + P -> LDS (bf16, swizzled 256B rows)
    char* Pb = sm + wid * 8192;   // wave-private 32x128 bf16 (overlays Q region)
#pragma unroll
    for (int m = 0; m < 2; m++) {
#pragma unroll
        for (int j = 0; j < 4; j++) {
            float e[8];
            float s1 = 0.f, s2 = 0.f;
#pragma unroll
            for (int n = 0; n < 8; n++) {
                int col = n * 16 + lo;
                float ev = __expf(sc[m][n][j]);
                e[n] = ev;
                if (col < 87) s1 += ev;
                else if (col < 127) s2 += ev;
            }
#pragma unroll
            for (int d = 1; d < 16; d <<= 1) {
                s1 += __shfl_xor(s1, d);
                s2 += __shfl_xor(s2, d);
            }
            float i1 = 1.f / s1, i2 = 1.f / s2;
            int row = m * 16 + hi * 4 + j;
#pragma unroll
            for (int n = 0; n < 8; n++) {
                int col = n * 16 + lo;
                float w = col < 87 ? i1 : (col < 127 ? i2 : 0.f);
                *(u16*)(Pb + ((row * 256 + col * 2) ^ ((row & 7) << 4))) = f2bf(e[n] * w);
            }
        }
    }
    __syncthreads();

    // PV: out[32 x 64] per wave; V fragments direct from global
    f32x4 o2[2][4];
#pragma unroll
    for (int m = 0; m < 2; m++)
#pragma unroll
        for (int n = 0; n < 4; n++)
            o2[m][n] = (f32x4){0.f, 0.f, 0.f, 0.f};
    __builtin_amdgcn_s_setprio(1);
#pragma unroll
    for (int kk = 0; kk < 4; kk++) {
        s16x8 pa[2];
#pragma unroll
        for (int m = 0; m < 2; m++) {
            int row = m * 16 + lo;
            pa[m] = *(const s16x8*)(Pb + ((row * 256 + (kk * 4 + hi) * 16) ^ ((row & 7) << 4)));
        }
#pragma unroll
        for (int n = 0; n < 4; n++) {
            int dr = n * 16 + lo;
            s16x8 vf = *(const s16x8*)(gv + ((dr * 256 + (kk * 4 + hi) * 16) ^ ((dr & 7) << 4)));
#pragma unroll
            for (int m = 0; m < 2; m++)
                o2[m][n] = __builtin_amdgcn_mfma_f32_16x16x32_bf16(pa[m], vf, o2[m][n], 0, 0, 0);
        }
    }
    __builtin_amdgcn_s_setprio(0);

#pragma unroll
    for (int m = 0; m < 2; m++)
#pragma unroll
        for (int n = 0; n < 4; n++)
#pragma unroll
            for (int j = 0; j < 4; j++) {
                size_t row = rs0 + m0r + m * 16 + hi * 4 + j;
                out[row * 1280 + h * 64 + n * 16 + lo] = f2bf(o2[m][n][j]);
            }
}

// ---------------- host ----------------
extern "C" void kernel_launch(void* const* d_in, const int* in_sizes, int n_in,
                              void* d_out, int out_size, void* d_ws, size_t ws_size,
                              hipStream_t stream)
{
    const float* hs  = (const float*)d_in[0];
    const float* ehs = (const float*)d_in[1];
    const float* tbg = (const float*)d_in[2];
    const float* ibg = (const float*)d_in[3];
    const float* Wq  = (const float*)d_in[4];
    const float* Wk  = (const float*)d_in[5];
    const float* Wv  = (const float*)d_in[6];
    const float* Wkt = (const float*)d_in[7];
    const float* Wvt = (const float*)d_in[8];
    const float* Wki = (const float*)d_in[9];
    const float* Wvi = (const float*)d_in[10];
    const float* Wo  = (const float*)d_in[11];
    const float* bo  = (const float*)d_in[12];
    float* out = (float*)d_out;

    const int B = 4, S = 4096, C = 1280, L = 77, Nt = 10, Ni = 40, Dc = 2048, Dt = 768;
    const int M = B * S;   // 16384

    char* p = (char*)d_ws;
    auto alloc = [&](size_t bytes) -> void* {
        void* r = (void*)p;
        p += (bytes + 255) & ~(size_t)255;
        return r;
    };
    u16* hs_b  = (u16*)alloc((size_t)M * C * 2);
    u16* q_b   = (u16*)alloc((size_t)M * C * 2);
    u16* at_b  = (u16*)alloc((size_t)M * C * 2);
    u16* WqT   = (u16*)alloc((size_t)C * C * 2);
    u16* WoT   = (u16*)alloc((size_t)C * C * 2);
    u16* WkT   = (u16*)alloc((size_t)C * Dc * 2);
    u16* WvT   = (u16*)alloc((size_t)C * Dc * 2);
    u16* WkiT  = (u16*)alloc((size_t)C * Dc * 2);
    u16* WviT  = (u16*)alloc((size_t)C * Dc * 2);
    u16* WktT  = (u16*)alloc((size_t)C * Dt * 2);
    u16* WvtT  = (u16*)alloc((size_t)C * Dt * 2);
    u16* ehs_b = (u16*)alloc((size_t)384 * Dc * 2);
    u16* tbg_b = (u16*)alloc((size_t)128 * Dt * 2);
    u16* ibg_b = (u16*)alloc((size_t)256 * Dc * 2);
    u16* Kimg  = (u16*)alloc((size_t)80 * 8192 * 2);
    u16* Vimg  = (u16*)alloc((size_t)80 * 8192 * 2);   // contiguous after Kimg

    // ---- zero KV images (slot 127 + any never-written bytes must be deterministic)
    hipMemsetAsync(Kimg, 0, (size_t)2 * 80 * 8192 * 2, stream);

    // ---- prep: casts + weight transposes (1 launch)
    PrepJobs pj;
    pj.cin[0] = hs;  pj.cout[0] = hs_b;
    pj.cin[1] = ehs; pj.cout[1] = ehs_b;
    pj.cin[2] = tbg; pj.cout[2] = tbg_b;
    pj.cin[3] = ibg; pj.cout[3] = ibg_b;
    long c0 = (long)M * C / 4, c1 = (long)B * L * Dc / 4,
         c2 = (long)B * Nt * Dt / 4, c3 = (long)B * Ni * Dc / 4;
    pj.cb[0] = c0; pj.cb[1] = c0 + c1; pj.cb[2] = c0 + c1 + c2;
    const float* wins[8] = {Wq, Wk, Wv, Wkt, Wvt, Wki, Wvi, Wo};
    u16* wouts[8]        = {WqT, WkT, WvT, WktT, WvtT, WkiT, WviT, WoT};
    int wks[8]           = {C, Dc, Dc, Dt, Dt, Dc, Dc, C};
    for (int i = 0; i < 8; i++) { pj.tin[i] = wins[i]; pj.tout[i] = wouts[i]; pj.tK[i] = wks[i]; }
    prep_kernel<<<21446 + 15360, 256, 0, stream>>>(pj);

    // ---- fused: KV projections -> images (120 blocks) + q projection (1024 blocks)
    FKV fk;
    const u16* kas[6]  = {ehs_b, ehs_b, tbg_b, tbg_b, ibg_b, ibg_b};
    const u16* kbs[6]  = {WkT, WvT, WktT, WvtT, WkiT, WviT};
    int kks[6]   = {Dc, Dc, Dt, Dt, Dc, Dc};
    int kms[6]   = {B * L, B * L, B * Nt, B * Nt, B * Ni, B * Ni};
    int kls[6]   = {L, L, Nt, Nt, Ni, Ni};
    int kbase[6] = {0, 0, 77, 77, 87, 87};
    for (int i = 0; i < 6; i++) {
        fk.A[i] = kas[i]; fk.Bt[i] = kbs[i];
        fk.K[i] = kks[i]; fk.M[i] = kms[i]; fk.L[i] = kls[i]; fk.base[i] = kbase[i];
    }
    fk.Kimg = Kimg; fk.Vimg = Vimg;
    gemm_fused<<<120 + 1024, 256, 0, stream>>>(hs_b, WqT, q_b, fk);

    // ---- attention (direct K/V reads, 32KB LDS)
    attn_mfma<<<dim3(S / 128, B * 20), 256, 0, stream>>>(q_b, Kimg, Vimg, at_b);

    // ---- output projection + bias + bf16 residual -> d_out (f32)
    gemm_8p<2><<<1024, 256, 0, stream>>>(at_b, WoT, out, bo, hs_b);
}

// Round 14
// 219.832 us; speedup vs baseline: 1.0380x; 1.0380x over previous
//
#include <hip/hip_runtime.h>

typedef unsigned short u16;
typedef __attribute__((ext_vector_type(4)))  float  f32x4;
typedef __attribute__((ext_vector_type(8)))  short  s16x8;
typedef __attribute__((ext_vector_type(8)))  unsigned short u16x8;
typedef __attribute__((ext_vector_type(4)))  unsigned short u16x4;
typedef __attribute__((ext_vector_type(4)))  float  f4;

#define AS1(p) ((const __attribute__((address_space(1))) void*)(p))
#define AS3(p) ((__attribute__((address_space(3))) void*)(p))

__device__ __forceinline__ float bf2f(u16 u) {
    unsigned v = ((unsigned)u) << 16;
    return __builtin_bit_cast(float, v);
}
__device__ __forceinline__ u16 f2bf(float f) {
    unsigned u = __builtin_bit_cast(unsigned, f);
    unsigned r = u + 0x7FFFu + ((u >> 16) & 1u);
    return (u16)(r >> 16);
}

#define SB __builtin_amdgcn_sched_barrier(0)
#define GATE0 do { asm volatile("s_waitcnt vmcnt(0)" ::: "memory"); SB; } while (0)

// ---------------- prep: casts (blocks 0..21445) + weight transposes (21446..36805) ----------------
struct PrepJobs {
    const float* cin[4]; u16* cout[4]; long cb[3];
    const float* tin[8]; u16* tout[8]; int tK[8];
};
__global__ __launch_bounds__(256) void prep_kernel(PrepJobs J) {
    const int bid = blockIdx.x;
    const int t = threadIdx.x;
    if (bid < 21446) {               // cast path (total4 = 5490176 = 21446*256 exactly)
        long i = (long)bid * 256 + t;
        int j = (i >= J.cb[0]) + (i >= J.cb[1]) + (i >= J.cb[2]);
        long k = i - (j ? J.cb[j - 1] : 0);
        f4 v = ((const f4*)J.cin[j])[k];
        u16x4 o;
        o[0] = f2bf(v.x); o[1] = f2bf(v.y); o[2] = f2bf(v.z); o[3] = f2bf(v.w);
        ((u16x4*)J.cout[j])[k] = o;
        return;
    }
    // transpose path
    int u = bid - 21446;
    int j = (u >= 1600) + (u >= 4160) + (u >= 6720) + (u >= 7680)
          + (u >= 8640) + (u >= 11200) + (u >= 13760);
    const int cumprev[8] = {0, 1600, 4160, 6720, 7680, 8640, 11200, 13760};
    int rem = u - cumprev[j];        // j is block-uniform scalar -> SGPR indexing
    const float* in = J.tin[j];
    u16* out = J.tout[j];
    const int K = J.tK[j];
    const int nb = (rem % 40) * 32;
    const int kb = (rem / 40) * 32;
    __shared__ float tile[32][33];
    const int tx = t & 31, ty = t >> 5;
#pragma unroll
    for (int r = 0; r < 32; r += 8)
        tile[ty + r][tx] = in[(size_t)(kb + ty + r) * 1280 + nb + tx];
    __syncthreads();
#pragma unroll
    for (int r = 0; r < 32; r += 8)
        out[(size_t)(nb + ty + r) * K + kb + tx] = f2bf(tile[tx][ty + r]);
}

// ================= standalone merged 2-phase 128x160 GEMM (out-projection) =================
// R8-VERIFIED schedule; see gemm_fused for the same structure.
template <int EPI>   // 0 = bf16 store; 2 = f32 + bias[col] + bf16 resid
__global__ __launch_bounds__(256, 2) void gemm_8p(
    const u16* __restrict__ A, const u16* __restrict__ Bt, void* __restrict__ outp,
    const float* __restrict__ bias, const u16* __restrict__ resid)
{
    const int K = 1280, N = 1280;
    __shared__ u16 lsA[2][128 * 64];
    __shared__ u16 lsB[2][160 * 64];

    const int bid = blockIdx.x;
    const int swz = (bid & 7) * 128 + (bid >> 3);
    const int m0 = (swz >> 3) * 128;
    const int n0 = (swz & 7) * 160;

    const int t = threadIdx.x;
    const int lane = t & 63, wid = t >> 6;
    const int wm = wid >> 1, wn = wid & 1;
    const int fr = lane & 15, hi = lane >> 4;
    const int fr7 = fr & 7;

    const int srow = t >> 3;
    const int sslot = (t & 7) ^ (srow & 7);
    const u16* gA = A  + (size_t)(m0 + srow) * K + sslot * 8;
    const u16* gB = Bt + (size_t)(n0 + srow) * K + sslot * 8;
    const size_t cK = (size_t)32 * K;

#define STGA(BUF, CC, KO) __builtin_amdgcn_global_load_lds(AS1(gA + (CC) * cK + (KO)), \
        AS3((char*)lsA + (BUF) * 16384 + (CC) * 4096 + t * 16), 16, 0, 0)
#define STGB(BUF, CC, KO) __builtin_amdgcn_global_load_lds(AS1(gB + (CC) * cK + (KO)), \
        AS3((char*)lsB + (BUF) * 20480 + (CC) * 4096 + t * 16), 16, 0, 0)
#define STG9(BUF, KO) do { \
    STGB(BUF, 0, KO); STGB(BUF, 1, KO); STGB(BUF, 2, KO); STGB(BUF, 3, KO); STGB(BUF, 4, KO); \
    STGA(BUF, 0, KO); STGA(BUF, 1, KO); STGA(BUF, 2, KO); STGA(BUF, 3, KO); \
} while (0)

    const char* lA0 = (const char*)lsA + (size_t)(wm * 64 + fr) * 128 + (((0 + hi) ^ fr7) << 4);
    const char* lA1 = (const char*)lsA + (size_t)(wm * 64 + fr) * 128 + (((4 + hi) ^ fr7) << 4);
    const char* lB0 = (const char*)lsB + (size_t)(wn * 80 + fr) * 128 + (((0 + hi) ^ fr7) << 4);
    const char* lB1 = (const char*)lsB + (size_t)(wn * 80 + fr) * 128 + (((4 + hi) ^ fr7) << 4);

    f32x4 acc[4][5];
#pragma unroll
    for (int i = 0; i < 4; i++)
#pragma unroll
        for (int j = 0; j < 5; j++)
            acc[i][j] = (f32x4){0.f, 0.f, 0.f, 0.f};

    s16x8 af[4], bfv[5];

#define DSRD2(BUF, KS) do { \
    _Pragma("unroll") for (int mi = 0; mi < 4; mi++) \
        af[mi] = *(const s16x8*)(((KS) ? lA1 : lA0) + (BUF) * 16384 + mi * 2048); \
    _Pragma("unroll") for (int nf = 0; nf < 5; nf++) \
        bfv[nf] = *(const s16x8*)(((KS) ? lB1 : lB0) + (BUF) * 20480 + nf * 2048); \
} while (0)
#define MM2 do { \
    _Pragma("unroll") for (int mi = 0; mi < 4; mi++) \
        _Pragma("unroll") for (int nf = 0; nf < 5; nf++) \
            acc[mi][nf] = __builtin_amdgcn_mfma_f32_16x16x32_bf16( \
                af[mi], bfv[nf], acc[mi][nf], 0, 0, 0); \
} while (0)
#define PHA(BUF, DOSTG, KO) do { \
    DSRD2(BUF, 0); \
    if (DOSTG) STG9((BUF) ^ 1, KO); \
    SB; __builtin_amdgcn_s_barrier(); SB; \
    asm volatile("s_waitcnt lgkmcnt(0)" ::: "memory"); SB; \
    __builtin_amdgcn_s_setprio(1); MM2; __builtin_amdgcn_s_setprio(0); SB; \
    __builtin_amdgcn_s_barrier(); SB; \
} while (0)
#define PHB(BUF, DOGATE) do { \
    DSRD2(BUF, 1); \
    SB; __builtin_amdgcn_s_barrier(); SB; \
    asm volatile("s_waitcnt lgkmcnt(0)" ::: "memory"); SB; \
    __builtin_amdgcn_s_setprio(1); MM2; __builtin_amdgcn_s_setprio(0); SB; \
    if (DOGATE) { GATE0; } \
    __builtin_amdgcn_s_barrier(); SB; \
} while (0)

    STG9(0, 0);
    GATE0;
    __builtin_amdgcn_s_barrier();
    SB;

    for (int i = 0; i < 9; i++) {
        const size_t k1 = (size_t)(2 * i + 1) * 64, k2 = k1 + 64;
        PHA(0, 1, k1); PHB(0, 1);
        PHA(1, 1, k2); PHB(1, 1);
    }
    PHA(0, 1, (size_t)19 * 64); PHB(0, 1);
    PHA(1, 0, 0);               PHB(1, 0);

#pragma unroll
    for (int mf = 0; mf < 4; mf++) {
#pragma unroll
        for (int nf = 0; nf < 5; nf++) {
#pragma unroll
            for (int j = 0; j < 4; j++) {
                int row = m0 + wm * 64 + mf * 16 + hi * 4 + j;
                int col = n0 + wn * 80 + nf * 16 + fr;
                float v = acc[mf][nf][j];
                if constexpr (EPI == 0) {
                    ((u16*)outp)[(size_t)row * N + col] = f2bf(v);
                } else {
                    ((float*)outp)[(size_t)row * N + col] =
                        v + bias[col] + bf2f(resid[(size_t)row * N + col]);
                }
            }
        }
    }
#undef STGA
#undef STGB
#undef STG9
#undef DSRD2
#undef MM2
#undef PHA
#undef PHB
}

// ================= fused launch: KV projections -> images (blocks 0..119) + q-proj (120..1143) =================
// KV path: R11-verified BK=64 dbuf 128x128 body; epilogue writes swizzled bf16 K/V
// images directly (K scaled 0.125). q path: byte-identical R8 schedule.
struct FKV {
    const u16* A[6]; const u16* Bt[6];
    int K[6], M[6], L[6], base[6];
    u16 *Kimg, *Vimg;
};
__global__ __launch_bounds__(256, 2) void gemm_fused(
    const u16* __restrict__ Aq, const u16* __restrict__ Bq, u16* __restrict__ outq, FKV J)
{
    __shared__ char smem[73728];
    const int t = threadIdx.x;
    const int lane = t & 63, wid = t >> 6;
    const int fr = lane & 15, hi = lane >> 4;
    const int fr7 = fr & 7;

    if (blockIdx.x >= 120) {
        // ---------------- q projection path ----------------
        const int K = 1280;
        const int bid = blockIdx.x - 120;
        const int swz = (bid & 7) * 128 + (bid >> 3);
        const int m0 = (swz >> 3) * 128;
        const int n0 = (swz & 7) * 160;
        const int wm = wid >> 1, wn = wid & 1;
        const int srow = t >> 3;
        const int sslot = (t & 7) ^ (srow & 7);
        const u16* gA = Aq + (size_t)(m0 + srow) * K + sslot * 8;
        const u16* gB = Bq + (size_t)(n0 + srow) * K + sslot * 8;
        const size_t cK = (size_t)32 * K;

#define QSTGA(BUF, CC, KO) __builtin_amdgcn_global_load_lds(AS1(gA + (CC) * cK + (KO)), \
        AS3(smem + (BUF) * 16384 + (CC) * 4096 + t * 16), 16, 0, 0)
#define QSTGB(BUF, CC, KO) __builtin_amdgcn_global_load_lds(AS1(gB + (CC) * cK + (KO)), \
        AS3(smem + 32768 + (BUF) * 20480 + (CC) * 4096 + t * 16), 16, 0, 0)
#define QSTG9(BUF, KO) do { \
    QSTGB(BUF, 0, KO); QSTGB(BUF, 1, KO); QSTGB(BUF, 2, KO); QSTGB(BUF, 3, KO); QSTGB(BUF, 4, KO); \
    QSTGA(BUF, 0, KO); QSTGA(BUF, 1, KO); QSTGA(BUF, 2, KO); QSTGA(BUF, 3, KO); \
} while (0)

        const char* lA0 = smem + (size_t)(wm * 64 + fr) * 128 + (((0 + hi) ^ fr7) << 4);
        const char* lA1 = smem + (size_t)(wm * 64 + fr) * 128 + (((4 + hi) ^ fr7) << 4);
        const char* lB0 = smem + 32768 + (size_t)(wn * 80 + fr) * 128 + (((0 + hi) ^ fr7) << 4);
        const char* lB1 = smem + 32768 + (size_t)(wn * 80 + fr) * 128 + (((4 + hi) ^ fr7) << 4);

        f32x4 acc[4][5];
#pragma unroll
        for (int i = 0; i < 4; i++)
#pragma unroll
            for (int j = 0; j < 5; j++)
                acc[i][j] = (f32x4){0.f, 0.f, 0.f, 0.f};

        s16x8 af[4], bfv[5];

#define QDSRD2(BUF, KS) do { \
    _Pragma("unroll") for (int mi = 0; mi < 4; mi++) \
        af[mi] = *(const s16x8*)(((KS) ? lA1 : lA0) + (BUF) * 16384 + mi * 2048); \
    _Pragma("unroll") for (int nf = 0; nf < 5; nf++) \
        bfv[nf] = *(const s16x8*)(((KS) ? lB1 : lB0) + (BUF) * 20480 + nf * 2048); \
} while (0)
#define QMM2 do { \
    _Pragma("unroll") for (int mi = 0; mi < 4; mi++) \
        _Pragma("unroll") for (int nf = 0; nf < 5; nf++) \
            acc[mi][nf] = __builtin_amdgcn_mfma_f32_16x16x32_bf16( \
                af[mi], bfv[nf], acc[mi][nf], 0, 0, 0); \
} while (0)
#define QPHA(BUF, DOSTG, KO) do { \
    QDSRD2(BUF, 0); \
    if (DOSTG) QSTG9((BUF) ^ 1, KO); \
    SB; __builtin_amdgcn_s_barrier(); SB; \
    asm volatile("s_waitcnt lgkmcnt(0)" ::: "memory"); SB; \
    __builtin_amdgcn_s_setprio(1); QMM2; __builtin_amdgcn_s_setprio(0); SB; \
    __builtin_amdgcn_s_barrier(); SB; \
} while (0)
#define QPHB(BUF, DOGATE) do { \
    QDSRD2(BUF, 1); \
    SB; __builtin_amdgcn_s_barrier(); SB; \
    asm volatile("s_waitcnt lgkmcnt(0)" ::: "memory"); SB; \
    __builtin_amdgcn_s_setprio(1); QMM2; __builtin_amdgcn_s_setprio(0); SB; \
    if (DOGATE) { GATE0; } \
    __builtin_amdgcn_s_barrier(); SB; \
} while (0)

        QSTG9(0, 0);
        GATE0;
        __builtin_amdgcn_s_barrier();
        SB;

        for (int i = 0; i < 9; i++) {
            const size_t k1 = (size_t)(2 * i + 1) * 64, k2 = k1 + 64;
            QPHA(0, 1, k1); QPHB(0, 1);
            QPHA(1, 1, k2); QPHB(1, 1);
        }
        QPHA(0, 1, (size_t)19 * 64); QPHB(0, 1);
        QPHA(1, 0, 0);               QPHB(1, 0);

#pragma unroll
        for (int mf = 0; mf < 4; mf++) {
#pragma unroll
            for (int nf = 0; nf < 5; nf++) {
#pragma unroll
                for (int j = 0; j < 4; j++) {
                    int row = m0 + wm * 64 + mf * 16 + hi * 4 + j;
                    int col = n0 + wn * 80 + nf * 16 + fr;
                    outq[(size_t)row * 1280 + col] = f2bf(acc[mf][nf][j]);
                }
            }
        }
#undef QSTGA
#undef QSTGB
#undef QSTG9
#undef QDSRD2
#undef QMM2
#undef QPHA
#undef QPHB
        return;
    }

    // ---------------- KV projection path (blocks 0..119) ----------------
    const int kvq = blockIdx.x;
    const int pn = kvq % 10;
    const int rem = kvq / 10;
    int j, bx;
    if (rem < 6)      { j = rem / 3;            bx = rem % 3; }
    else if (rem < 8) { j = rem - 4;            bx = 0; }
    else              { j = 4 + ((rem - 8) >> 1); bx = (rem - 8) & 1; }

    const u16* A  = J.A[j];
    const u16* Bt = J.Bt[j];
    const int K = J.K[j], Mj = J.M[j], Lj = J.L[j], basej = J.base[j];
    const int m0 = bx * 128, n0 = pn * 128;
    const int wr = wid >> 1, wc = wid & 1;
    const int fq = hi;

    f32x4 acc[4][4];
#pragma unroll
    for (int i = 0; i < 4; i++)
#pragma unroll
        for (int jj = 0; jj < 4; jj++)
            acc[i][jj] = (f32x4){0.f, 0.f, 0.f, 0.f};

    const int arow = t >> 3;
    const int aslot = (t & 7) ^ (arow & 7);
    const u16* gA = A  + (size_t)(m0 + arow) * K + aslot * 8;
    const u16* gB = Bt + (size_t)(n0 + arow) * K + aslot * 8;
    const size_t cK = (size_t)32 * K;

#define KSTAGE(buf, k0) do { \
    _Pragma("unroll") for (int c = 0; c < 4; c++) { \
        __builtin_amdgcn_global_load_lds(AS1(gA + c * cK + (k0)), AS3(smem + (buf) * 16384 + c * 4096 + t * 16), 16, 0, 0); \
        __builtin_amdgcn_global_load_lds(AS1(gB + c * cK + (k0)), AS3(smem + 32768 + (buf) * 16384 + c * 4096 + t * 16), 16, 0, 0); \
    } \
} while (0)

    const char* lA0 = smem + (size_t)(wr * 64 + fr) * 128 + (((0 + fq) ^ fr7) << 4);
    const char* lA1 = smem + (size_t)(wr * 64 + fr) * 128 + (((4 + fq) ^ fr7) << 4);
    const char* lB0 = smem + 32768 + (size_t)(wc * 64 + fr) * 128 + (((0 + fq) ^ fr7) << 4);
    const char* lB1 = smem + 32768 + (size_t)(wc * 64 + fr) * 128 + (((4 + fq) ^ fr7) << 4);

    KSTAGE(0, 0);
    __syncthreads();

    int cur = 0;
    for (int k0 = 0; k0 < K; k0 += 64) {
        if (k0 + 64 < K) KSTAGE(cur ^ 1, k0 + 64);

#pragma unroll
        for (int ks = 0; ks < 2; ks++) {
            s16x8 af[4], bfr[4];
#pragma unroll
            for (int i = 0; i < 4; i++) {
                af[i]  = *(const s16x8*)((ks ? lA1 : lA0) + cur * 16384 + i * 2048);
                bfr[i] = *(const s16x8*)((ks ? lB1 : lB0) + cur * 16384 + i * 2048);
            }
#pragma unroll
            for (int mi = 0; mi < 4; mi++)
#pragma unroll
                for (int ni = 0; ni < 4; ni++)
                    acc[mi][ni] = __builtin_amdgcn_mfma_f32_16x16x32_bf16(af[mi], bfr[ni], acc[mi][ni], 0, 0, 0);
        }

        __syncthreads();
        cur ^= 1;
    }
#undef KSTAGE

    // epilogue: scatter into swizzled bf16 images (memset pre-zeroed slot 127 & padding)
    const bool isV = (j & 1) != 0;
    u16* img = isV ? J.Vimg : J.Kimg;
    const float scl = isV ? 1.0f : 0.125f;
#pragma unroll
    for (int mi = 0; mi < 4; mi++) {
#pragma unroll
        for (int ni = 0; ni < 4; ni++) {
#pragma unroll
            for (int jj = 0; jj < 4; jj++) {
                int row = m0 + wr * 64 + mi * 16 + fq * 4 + jj;
                if (row < Mj) {
                    int col = n0 + wc * 64 + ni * 16 + fr;
                    int b = row / Lj, kl = row - b * Lj, kg = basej + kl;
                    int h = col >> 6, d = col & 63;
                    size_t bhoff = (size_t)(b * 20 + h) * 16384;
                    int off = isV ? (((d * 256 + (kg >> 3) * 16) ^ ((d & 7) << 4)) + (kg & 7) * 2)
                                  : (((kg * 128 + (d >> 3) * 16) ^ ((kg & 7) << 4)) + (d & 7) * 2);
                    *(u16*)((char*)img + bhoff + off) = f2bf(acc[mi][ni][jj] * scl);
                }
            }
        }
    }
}

// ---------------- MFMA attention (R12-verified: staged K/V via global_load_lds) ----------------
__global__ __launch_bounds__(256) void attn_mfma(
    const u16* __restrict__ q, const u16* __restrict__ Kimg,
    const u16* __restrict__ Vimg, u16* __restrict__ out)
{
    __shared__ char sm[49152];
    char* Qb = sm;
    char* Kb = sm + 16384;
    char* Vb = sm + 32768;

    const int t = threadIdx.x;
    const int lane = t & 63, wid = t >> 6;
    const int lo = lane & 15, hi = lane >> 4;
    const int s0 = blockIdx.x * 128;
    const int bh = blockIdx.y;
    const int b = bh / 20, h = bh - b * 20;
    const size_t rs0 = (size_t)b * 4096 + s0;

    const u16* gk = Kimg + (size_t)bh * 8192;
    const u16* gv = Vimg + (size_t)bh * 8192;
#pragma unroll
    for (int i = 0; i < 4; i++) {
        int ch = t + i * 256;
        __builtin_amdgcn_global_load_lds(AS1(gk + (size_t)ch * 8), AS3(Kb + ch * 16), 16, 0, 0);
        __builtin_amdgcn_global_load_lds(AS1(gv + (size_t)ch * 8), AS3(Vb + ch * 16), 16, 0, 0);
    }
#pragma unroll
    for (int i = 0; i < 4; i++) {
        int ch = t + i * 256;
        int r = ch >> 3, cs = ch & 7;
        u16x8 v = *(const u16x8*)(q + (rs0 + r) * 1280 + h * 64 + cs * 8);
        *(u16x8*)(Qb + ((r * 128 + cs * 16) ^ ((r & 7) << 4))) = v;
    }
    __syncthreads();

    const int m0r = wid * 32;
    s16x8 qf[2][2];
#pragma unroll
    for (int m = 0; m < 2; m++)
#pragma unroll
        for (int kf = 0; kf < 2; kf++) {
            int r = m0r + m * 16 + lo;
            qf[m][kf] = *(const s16x8*)(Qb + ((r * 128 + (kf * 4 + hi) * 16) ^ ((r & 7) << 4)));
        }
    f32x4 sc[2][8];
#pragma unroll
    for (int m = 0; m < 2; m++)
#pragma unroll
        for (int n = 0; n < 8; n++)
            sc[m][n] = (f32x4){0.f, 0.f, 0.f, 0.f};
#pragma unroll
    for (int kf = 0; kf < 2; kf++)
#pragma unroll
        for (int n = 0; n < 8; n++) {
            int r = n * 16 + lo;
            s16x8 kf8 = *(const s16x8*)(Kb + ((r * 128 + (kf * 4 + hi) * 16) ^ ((r & 7) << 4)));
#pragma unroll
            for (int m = 0; m < 2; m++)
                sc[m][n] = __builtin_amdgcn_mfma_f32_16x16x32_bf16(qf[m][kf], kf8, sc[m][n], 0, 0, 0);
        }
    __syncthreads();

    char* Pb = sm + wid * 8192;
#pragma unroll
    for (int m = 0; m < 2; m++) {
#pragma unroll
        for (int j = 0; j < 4; j++) {
            float e[8];
            float s1 = 0.f, s2 = 0.f;
#pragma unroll
            for (int n = 0; n < 8; n++) {
                int col = n * 16 + lo;
                float ev = __expf(sc[m][n][j]);
                e[n] = ev;
                if (col < 87) s1 += ev;
                else if (col < 127) s2 += ev;
            }
#pragma unroll
            for (int d = 1; d < 16; d <<= 1) {
                s1 += __shfl_xor(s1, d);
                s2 += __shfl_xor(s2, d);
            }
            float i1 = 1.f / s1, i2 = 1.f / s2;
            int row = m * 16 + hi * 4 + j;
#pragma unroll
            for (int n = 0; n < 8; n++) {
                int col = n * 16 + lo;
                float w = col < 87 ? i1 : (col < 127 ? i2 : 0.f);
                *(u16*)(Pb + ((row * 256 + col * 2) ^ ((row & 7) << 4))) = f2bf(e[n] * w);
            }
        }
    }
    __syncthreads();

    f32x4 o2[2][4];
#pragma unroll
    for (int m = 0; m < 2; m++)
#pragma unroll
        for (int n = 0; n < 4; n++)
            o2[m][n] = (f32x4){0.f, 0.f, 0.f, 0.f};
#pragma unroll
    for (int kk = 0; kk < 4; kk++) {
        s16x8 pa[2];
#pragma unroll
        for (int m = 0; m < 2; m++) {
            int row = m * 16 + lo;
            pa[m] = *(const s16x8*)(Pb + ((row * 256 + (kk * 4 + hi) * 16) ^ ((row & 7) << 4)));
        }
#pragma unroll
        for (int n = 0; n < 4; n++) {
            int dr = n * 16 + lo;
            s16x8 vf = *(const s16x8*)(Vb + ((dr * 256 + (kk * 4 + hi) * 16) ^ ((dr & 7) << 4)));
#pragma unroll
            for (int m = 0; m < 2; m++)
                o2[m][n] = __builtin_amdgcn_mfma_f32_16x16x32_bf16(pa[m], vf, o2[m][n], 0, 0, 0);
        }
    }

#pragma unroll
    for (int m = 0; m < 2; m++)
#pragma unroll
        for (int n = 0; n < 4; n++)
#pragma unroll
            for (int j = 0; j < 4; j++) {
                size_t row = rs0 + m0r + m * 16 + hi * 4 + j;
                out[row * 1280 + h * 64 + n * 16 + lo] = f2bf(o2[m][n][j]);
            }
}

// ---------------- host ----------------
extern "C" void kernel_launch(void* const* d_in, const int* in_sizes, int n_in,
                              void* d_out, int out_size, void* d_ws, size_t ws_size,
                              hipStream_t stream)
{
    const float* hs  = (const float*)d_in[0];
    const float* ehs = (const float*)d_in[1];
    const float* tbg = (const float*)d_in[2];
    const float* ibg = (const float*)d_in[3];
    const float* Wq  = (const float*)d_in[4];
    const float* Wk  = (const float*)d_in[5];
    const float* Wv  = (const float*)d_in[6];
    const float* Wkt = (const float*)d_in[7];
    const float* Wvt = (const float*)d_in[8];
    const float* Wki = (const float*)d_in[9];
    const float* Wvi = (const float*)d_in[10];
    const float* Wo  = (const float*)d_in[11];
    const float* bo  = (const float*)d_in[12];
    float* out = (float*)d_out;

    const int B = 4, S = 4096, C = 1280, L = 77, Nt = 10, Ni = 40, Dc = 2048, Dt = 768;
    const int M = B * S;   // 16384

    char* p = (char*)d_ws;
    auto alloc = [&](size_t bytes) -> void* {
        void* r = (void*)p;
        p += (bytes + 255) & ~(size_t)255;
        return r;
    };
    u16* hs_b  = (u16*)alloc((size_t)M * C * 2);
    u16* q_b   = (u16*)alloc((size_t)M * C * 2);
    u16* at_b  = (u16*)alloc((size_t)M * C * 2);
    u16* WqT   = (u16*)alloc((size_t)C * C * 2);
    u16* WoT   = (u16*)alloc((size_t)C * C * 2);
    u16* WkT   = (u16*)alloc((size_t)C * Dc * 2);
    u16* WvT   = (u16*)alloc((size_t)C * Dc * 2);
    u16* WkiT  = (u16*)alloc((size_t)C * Dc * 2);
    u16* WviT  = (u16*)alloc((size_t)C * Dc * 2);
    u16* WktT  = (u16*)alloc((size_t)C * Dt * 2);
    u16* WvtT  = (u16*)alloc((size_t)C * Dt * 2);
    u16* ehs_b = (u16*)alloc((size_t)384 * Dc * 2);
    u16* tbg_b = (u16*)alloc((size_t)128 * Dt * 2);
    u16* ibg_b = (u16*)alloc((size_t)256 * Dc * 2);
    u16* Kimg  = (u16*)alloc((size_t)80 * 8192 * 2);
    u16* Vimg  = (u16*)alloc((size_t)80 * 8192 * 2);   // contiguous after Kimg

    // ---- zero KV images (slot 127 + any never-written bytes must be deterministic)
    hipMemsetAsync(Kimg, 0, (size_t)2 * 80 * 8192 * 2, stream);

    // ---- prep: casts + weight transposes (1 launch)
    PrepJobs pj;
    pj.cin[0] = hs;  pj.cout[0] = hs_b;
    pj.cin[1] = ehs; pj.cout[1] = ehs_b;
    pj.cin[2] = tbg; pj.cout[2] = tbg_b;
    pj.cin[3] = ibg; pj.cout[3] = ibg_b;
    long c0 = (long)M * C / 4, c1 = (long)B * L * Dc / 4,
         c2 = (long)B * Nt * Dt / 4, c3 = (long)B * Ni * Dc / 4;
    pj.cb[0] = c0; pj.cb[1] = c0 + c1; pj.cb[2] = c0 + c1 + c2;
    const float* wins[8] = {Wq, Wk, Wv, Wkt, Wvt, Wki, Wvi, Wo};
    u16* wouts[8]        = {WqT, WkT, WvT, WktT, WvtT, WkiT, WviT, WoT};
    int wks[8]           = {C, Dc, Dc, Dt, Dt, Dc, Dc, C};
    for (int i = 0; i < 8; i++) { pj.tin[i] = wins[i]; pj.tout[i] = wouts[i]; pj.tK[i] = wks[i]; }
    prep_kernel<<<21446 + 15360, 256, 0, stream>>>(pj);

    // ---- fused: KV projections -> images (120 blocks) + q projection (1024 blocks)
    FKV fk;
    const u16* kas[6]  = {ehs_b, ehs_b, tbg_b, tbg_b, ibg_b, ibg_b};
    const u16* kbs[6]  = {WkT, WvT, WktT, WvtT, WkiT, WviT};
    int kks[6]   = {Dc, Dc, Dt, Dt, Dc, Dc};
    int kms[6]   = {B * L, B * L, B * Nt, B * Nt, B * Ni, B * Ni};
    int kls[6]   = {L, L, Nt, Nt, Ni, Ni};
    int kbase[6] = {0, 0, 77, 77, 87, 87};
    for (int i = 0; i < 6; i++) {
        fk.A[i] = kas[i]; fk.Bt[i] = kbs[i];
        fk.K[i] = kks[i]; fk.M[i] = kms[i]; fk.L[i] = kls[i]; fk.base[i] = kbase[i];
    }
    fk.Kimg = Kimg; fk.Vimg = Vimg;
    gemm_fused<<<120 + 1024, 256, 0, stream>>>(hs_b, WqT, q_b, fk);

    // ---- attention (staged K/V, 48KB LDS)
    attn_mfma<<<dim3(S / 128, B * 20), 256, 0, stream>>>(q_b, Kimg, Vimg, at_b);

    // ---- output projection + bias + bf16 residual -> d_out (f32)
    gemm_8p<2><<<1024, 256, 0, stream>>>(at_b, WoT, out, bo, hs_b);
}

// Round 15
// 216.536 us; speedup vs baseline: 1.0538x; 1.0152x over previous
//
#include <hip/hip_runtime.h>

typedef unsigned short u16;
typedef __attribute__((ext_vector_type(4)))  float  f32x4;
typedef __attribute__((ext_vector_type(8)))  short  s16x8;
typedef __attribute__((ext_vector_type(8)))  unsigned short u16x8;
typedef __attribute__((ext_vector_type(4)))  unsigned short u16x4;
typedef __attribute__((ext_vector_type(4)))  float  f4;

#define AS1(p) ((const __attribute__((address_space(1))) void*)(p))
#define AS3(p) ((__attribute__((address_space(3))) void*)(p))

__device__ __forceinline__ float bf2f(u16 u) {
    unsigned v = ((unsigned)u) << 16;
    return __builtin_bit_cast(float, v);
}
__device__ __forceinline__ u16 f2bf(float f) {
    unsigned u = __builtin_bit_cast(unsigned, f);
    unsigned r = u + 0x7FFFu + ((u >> 16) & 1u);
    return (u16)(r >> 16);
}

#define SB __builtin_amdgcn_sched_barrier(0)
#define GATE0 do { asm volatile("s_waitcnt vmcnt(0)" ::: "memory"); SB; } while (0)

// ---- prep: casts (0..21445) + weight transposes (21446..36805) + image-zero (36806..37445) ----
struct PrepJobs {
    const float* cin[4]; u16* cout[4]; long cb[3];
    const float* tin[8]; u16* tout[8]; int tK[8];
    char* zbase;   // KV images base; 640 blocks x 4096B of zeros (replaces hipMemsetAsync)
};
__global__ __launch_bounds__(256) void prep_kernel(PrepJobs J) {
    const int bid = blockIdx.x;
    const int t = threadIdx.x;
    if (bid < 21446) {               // cast path (total4 = 5490176 = 21446*256 exactly)
        long i = (long)bid * 256 + t;
        int j = (i >= J.cb[0]) + (i >= J.cb[1]) + (i >= J.cb[2]);
        long k = i - (j ? J.cb[j - 1] : 0);
        f4 v = ((const f4*)J.cin[j])[k];
        u16x4 o;
        o[0] = f2bf(v.x); o[1] = f2bf(v.y); o[2] = f2bf(v.z); o[3] = f2bf(v.w);
        ((u16x4*)J.cout[j])[k] = o;
        return;
    }
    if (bid >= 36806) {              // image-zero path: 640 blocks x 256 thr x 16B = 2,621,440 B
        long off = (long)(bid - 36806) * 4096 + t * 16;
        *(u16x8*)(J.zbase + off) = (u16x8){0,0,0,0,0,0,0,0};
        return;
    }
    // transpose path
    int u = bid - 21446;
    int j = (u >= 1600) + (u >= 4160) + (u >= 6720) + (u >= 7680)
          + (u >= 8640) + (u >= 11200) + (u >= 13760);
    const int cumprev[8] = {0, 1600, 4160, 6720, 7680, 8640, 11200, 13760};
    int rem = u - cumprev[j];        // j is block-uniform scalar -> SGPR indexing
    const float* in = J.tin[j];
    u16* out = J.tout[j];
    const int K = J.tK[j];
    const int nb = (rem % 40) * 32;
    const int kb = (rem / 40) * 32;
    __shared__ float tile[32][33];
    const int tx = t & 31, ty = t >> 5;
#pragma unroll
    for (int r = 0; r < 32; r += 8)
        tile[ty + r][tx] = in[(size_t)(kb + ty + r) * 1280 + nb + tx];
    __syncthreads();
#pragma unroll
    for (int r = 0; r < 32; r += 8)
        out[(size_t)(nb + ty + r) * K + kb + tx] = f2bf(tile[tx][ty + r]);
}

// ================= standalone merged 2-phase 128x160 GEMM (out-projection) =================
// R8-VERIFIED schedule; see gemm_fused for the same structure.
template <int EPI>   // 0 = bf16 store; 2 = f32 + bias[col] + bf16 resid
__global__ __launch_bounds__(256, 2) void gemm_8p(
    const u16* __restrict__ A, const u16* __restrict__ Bt, void* __restrict__ outp,
    const float* __restrict__ bias, const u16* __restrict__ resid)
{
    const int K = 1280, N = 1280;
    __shared__ u16 lsA[2][128 * 64];
    __shared__ u16 lsB[2][160 * 64];

    const int bid = blockIdx.x;
    const int swz = (bid & 7) * 128 + (bid >> 3);
    const int m0 = (swz >> 3) * 128;
    const int n0 = (swz & 7) * 160;

    const int t = threadIdx.x;
    const int lane = t & 63, wid = t >> 6;
    const int wm = wid >> 1, wn = wid & 1;
    const int fr = lane & 15, hi = lane >> 4;
    const int fr7 = fr & 7;

    const int srow = t >> 3;
    const int sslot = (t & 7) ^ (srow & 7);
    const u16* gA = A  + (size_t)(m0 + srow) * K + sslot * 8;
    const u16* gB = Bt + (size_t)(n0 + srow) * K + sslot * 8;
    const size_t cK = (size_t)32 * K;

#define STGA(BUF, CC, KO) __builtin_amdgcn_global_load_lds(AS1(gA + (CC) * cK + (KO)), \
        AS3((char*)lsA + (BUF) * 16384 + (CC) * 4096 + t * 16), 16, 0, 0)
#define STGB(BUF, CC, KO) __builtin_amdgcn_global_load_lds(AS1(gB + (CC) * cK + (KO)), \
        AS3((char*)lsB + (BUF) * 20480 + (CC) * 4096 + t * 16), 16, 0, 0)
#define STG9(BUF, KO) do { \
    STGB(BUF, 0, KO); STGB(BUF, 1, KO); STGB(BUF, 2, KO); STGB(BUF, 3, KO); STGB(BUF, 4, KO); \
    STGA(BUF, 0, KO); STGA(BUF, 1, KO); STGA(BUF, 2, KO); STGA(BUF, 3, KO); \
} while (0)

    const char* lA0 = (const char*)lsA + (size_t)(wm * 64 + fr) * 128 + (((0 + hi) ^ fr7) << 4);
    const char* lA1 = (const char*)lsA + (size_t)(wm * 64 + fr) * 128 + (((4 + hi) ^ fr7) << 4);
    const char* lB0 = (const char*)lsB + (size_t)(wn * 80 + fr) * 128 + (((0 + hi) ^ fr7) << 4);
    const char* lB1 = (const char*)lsB + (size_t)(wn * 80 + fr) * 128 + (((4 + hi) ^ fr7) << 4);

    f32x4 acc[4][5];
#pragma unroll
    for (int i = 0; i < 4; i++)
#pragma unroll
        for (int j = 0; j < 5; j++)
            acc[i][j] = (f32x4){0.f, 0.f, 0.f, 0.f};

    s16x8 af[4], bfv[5];

#define DSRD2(BUF, KS) do { \
    _Pragma("unroll") for (int mi = 0; mi < 4; mi++) \
        af[mi] = *(const s16x8*)(((KS) ? lA1 : lA0) + (BUF) * 16384 + mi * 2048); \
    _Pragma("unroll") for (int nf = 0; nf < 5; nf++) \
        bfv[nf] = *(const s16x8*)(((KS) ? lB1 : lB0) + (BUF) * 20480 + nf * 2048); \
} while (0)
#define MM2 do { \
    _Pragma("unroll") for (int mi = 0; mi < 4; mi++) \
        _Pragma("unroll") for (int nf = 0; nf < 5; nf++) \
            acc[mi][nf] = __builtin_amdgcn_mfma_f32_16x16x32_bf16( \
                af[mi], bfv[nf], acc[mi][nf], 0, 0, 0); \
} while (0)
#define PHA(BUF, DOSTG, KO) do { \
    DSRD2(BUF, 0); \
    if (DOSTG) STG9((BUF) ^ 1, KO); \
    SB; __builtin_amdgcn_s_barrier(); SB; \
    asm volatile("s_waitcnt lgkmcnt(0)" ::: "memory"); SB; \
    __builtin_amdgcn_s_setprio(1); MM2; __builtin_amdgcn_s_setprio(0); SB; \
    __builtin_amdgcn_s_barrier(); SB; \
} while (0)
#define PHB(BUF, DOGATE) do { \
    DSRD2(BUF, 1); \
    SB; __builtin_amdgcn_s_barrier(); SB; \
    asm volatile("s_waitcnt lgkmcnt(0)" ::: "memory"); SB; \
    __builtin_amdgcn_s_setprio(1); MM2; __builtin_amdgcn_s_setprio(0); SB; \
    if (DOGATE) { GATE0; } \
    __builtin_amdgcn_s_barrier(); SB; \
} while (0)

    STG9(0, 0);
    GATE0;
    __builtin_amdgcn_s_barrier();
    SB;

    for (int i = 0; i < 9; i++) {
        const size_t k1 = (size_t)(2 * i + 1) * 64, k2 = k1 + 64;
        PHA(0, 1, k1); PHB(0, 1);
        PHA(1, 1, k2); PHB(1, 1);
    }
    PHA(0, 1, (size_t)19 * 64); PHB(0, 1);
    PHA(1, 0, 0);               PHB(1, 0);

#pragma unroll
    for (int mf = 0; mf < 4; mf++) {
#pragma unroll
        for (int nf = 0; nf < 5; nf++) {
#pragma unroll
            for (int j = 0; j < 4; j++) {
                int row = m0 + wm * 64 + mf * 16 + hi * 4 + j;
                int col = n0 + wn * 80 + nf * 16 + fr;
                float v = acc[mf][nf][j];
                if constexpr (EPI == 0) {
                    ((u16*)outp)[(size_t)row * N + col] = f2bf(v);
                } else {
                    ((float*)outp)[(size_t)row * N + col] =
                        v + bias[col] + bf2f(resid[(size_t)row * N + col]);
                }
            }
        }
    }
#undef STGA
#undef STGB
#undef STG9
#undef DSRD2
#undef MM2
#undef PHA
#undef PHB
}

// ================= fused launch: KV projections -> images (blocks 0..119) + q-proj (120..1143) =================
struct FKV {
    const u16* A[6]; const u16* Bt[6];
    int K[6], M[6], L[6], base[6];
    u16 *Kimg, *Vimg;
};
__global__ __launch_bounds__(256, 2) void gemm_fused(
    const u16* __restrict__ Aq, const u16* __restrict__ Bq, u16* __restrict__ outq, FKV J)
{
    __shared__ char smem[73728];
    const int t = threadIdx.x;
    const int lane = t & 63, wid = t >> 6;
    const int fr = lane & 15, hi = lane >> 4;
    const int fr7 = fr & 7;

    if (blockIdx.x >= 120) {
        // ---------------- q projection path ----------------
        const int K = 1280;
        const int bid = blockIdx.x - 120;
        const int swz = (bid & 7) * 128 + (bid >> 3);
        const int m0 = (swz >> 3) * 128;
        const int n0 = (swz & 7) * 160;
        const int wm = wid >> 1, wn = wid & 1;
        const int srow = t >> 3;
        const int sslot = (t & 7) ^ (srow & 7);
        const u16* gA = Aq + (size_t)(m0 + srow) * K + sslot * 8;
        const u16* gB = Bq + (size_t)(n0 + srow) * K + sslot * 8;
        const size_t cK = (size_t)32 * K;

#define QSTGA(BUF, CC, KO) __builtin_amdgcn_global_load_lds(AS1(gA + (CC) * cK + (KO)), \
        AS3(smem + (BUF) * 16384 + (CC) * 4096 + t * 16), 16, 0, 0)
#define QSTGB(BUF, CC, KO) __builtin_amdgcn_global_load_lds(AS1(gB + (CC) * cK + (KO)), \
        AS3(smem + 32768 + (BUF) * 20480 + (CC) * 4096 + t * 16), 16, 0, 0)
#define QSTG9(BUF, KO) do { \
    QSTGB(BUF, 0, KO); QSTGB(BUF, 1, KO); QSTGB(BUF, 2, KO); QSTGB(BUF, 3, KO); QSTGB(BUF, 4, KO); \
    QSTGA(BUF, 0, KO); QSTGA(BUF, 1, KO); QSTGA(BUF, 2, KO); QSTGA(BUF, 3, KO); \
} while (0)

        const char* lA0 = smem + (size_t)(wm * 64 + fr) * 128 + (((0 + hi) ^ fr7) << 4);
        const char* lA1 = smem + (size_t)(wm * 64 + fr) * 128 + (((4 + hi) ^ fr7) << 4);
        const char* lB0 = smem + 32768 + (size_t)(wn * 80 + fr) * 128 + (((0 + hi) ^ fr7) << 4);
        const char* lB1 = smem + 32768 + (size_t)(wn * 80 + fr) * 128 + (((4 + hi) ^ fr7) << 4);

        f32x4 acc[4][5];
#pragma unroll
        for (int i = 0; i < 4; i++)
#pragma unroll
            for (int j = 0; j < 5; j++)
                acc[i][j] = (f32x4){0.f, 0.f, 0.f, 0.f};

        s16x8 af[4], bfv[5];

#define QDSRD2(BUF, KS) do { \
    _Pragma("unroll") for (int mi = 0; mi < 4; mi++) \
        af[mi] = *(const s16x8*)(((KS) ? lA1 : lA0) + (BUF) * 16384 + mi * 2048); \
    _Pragma("unroll") for (int nf = 0; nf < 5; nf++) \
        bfv[nf] = *(const s16x8*)(((KS) ? lB1 : lB0) + (BUF) * 20480 + nf * 2048); \
} while (0)
#define QMM2 do { \
    _Pragma("unroll") for (int mi = 0; mi < 4; mi++) \
        _Pragma("unroll") for (int nf = 0; nf < 5; nf++) \
            acc[mi][nf] = __builtin_amdgcn_mfma_f32_16x16x32_bf16( \
                af[mi], bfv[nf], acc[mi][nf], 0, 0, 0); \
} while (0)
#define QPHA(BUF, DOSTG, KO) do { \
    QDSRD2(BUF, 0); \
    if (DOSTG) QSTG9((BUF) ^ 1, KO); \
    SB; __builtin_amdgcn_s_barrier(); SB; \
    asm volatile("s_waitcnt lgkmcnt(0)" ::: "memory"); SB; \
    __builtin_amdgcn_s_setprio(1); QMM2; __builtin_amdgcn_s_setprio(0); SB; \
    __builtin_amdgcn_s_barrier(); SB; \
} while (0)
#define QPHB(BUF, DOGATE) do { \
    QDSRD2(BUF, 1); \
    SB; __builtin_amdgcn_s_barrier(); SB; \
    asm volatile("s_waitcnt lgkmcnt(0)" ::: "memory"); SB; \
    __builtin_amdgcn_s_setprio(1); QMM2; __builtin_amdgcn_s_setprio(0); SB; \
    if (DOGATE) { GATE0; } \
    __builtin_amdgcn_s_barrier(); SB; \
} while (0)

        QSTG9(0, 0);
        GATE0;
        __builtin_amdgcn_s_barrier();
        SB;

        for (int i = 0; i < 9; i++) {
            const size_t k1 = (size_t)(2 * i + 1) * 64, k2 = k1 + 64;
            QPHA(0, 1, k1); QPHB(0, 1);
            QPHA(1, 1, k2); QPHB(1, 1);
        }
        QPHA(0, 1, (size_t)19 * 64); QPHB(0, 1);
        QPHA(1, 0, 0);               QPHB(1, 0);

#pragma unroll
        for (int mf = 0; mf < 4; mf++) {
#pragma unroll
            for (int nf = 0; nf < 5; nf++) {
#pragma unroll
                for (int j = 0; j < 4; j++) {
                    int row = m0 + wm * 64 + mf * 16 + hi * 4 + j;
                    int col = n0 + wn * 80 + nf * 16 + fr;
                    outq[(size_t)row * 1280 + col] = f2bf(acc[mf][nf][j]);
                }
            }
        }
#undef QSTGA
#undef QSTGB
#undef QSTG9
#undef QDSRD2
#undef QMM2
#undef QPHA
#undef QPHB
        return;
    }

    // ---------------- KV projection path (blocks 0..119) ----------------
    const int kvq = blockIdx.x;
    const int pn = kvq % 10;
    const int rem = kvq / 10;
    int j, bx;
    if (rem < 6)      { j = rem / 3;            bx = rem % 3; }
    else if (rem < 8) { j = rem - 4;            bx = 0; }
    else              { j = 4 + ((rem - 8) >> 1); bx = (rem - 8) & 1; }

    const u16* A  = J.A[j];
    const u16* Bt = J.Bt[j];
    const int K = J.K[j], Mj = J.M[j], Lj = J.L[j], basej = J.base[j];
    const int m0 = bx * 128, n0 = pn * 128;
    const int wr = wid >> 1, wc = wid & 1;
    const int fq = hi;

    f32x4 acc[4][4];
#pragma unroll
    for (int i = 0; i < 4; i++)
#pragma unroll
        for (int jj = 0; jj < 4; jj++)
            acc[i][jj] = (f32x4){0.f, 0.f, 0.f, 0.f};

    const int arow = t >> 3;
    const int aslot = (t & 7) ^ (arow & 7);
    const u16* gA = A  + (size_t)(m0 + arow) * K + aslot * 8;
    const u16* gB = Bt + (size_t)(n0 + arow) * K + aslot * 8;
    const size_t cK = (size_t)32 * K;

#define KSTAGE(buf, k0) do { \
    _Pragma("unroll") for (int c = 0; c < 4; c++) { \
        __builtin_amdgcn_global_load_lds(AS1(gA + c * cK + (k0)), AS3(smem + (buf) * 16384 + c * 4096 + t * 16), 16, 0, 0); \
        __builtin_amdgcn_global_load_lds(AS1(gB + c * cK + (k0)), AS3(smem + 32768 + (buf) * 16384 + c * 4096 + t * 16), 16, 0, 0); \
    } \
} while (0)

    const char* lA0 = smem + (size_t)(wr * 64 + fr) * 128 + (((0 + fq) ^ fr7) << 4);
    const char* lA1 = smem + (size_t)(wr * 64 + fr) * 128 + (((4 + fq) ^ fr7) << 4);
    const char* lB0 = smem + 32768 + (size_t)(wc * 64 + fr) * 128 + (((0 + fq) ^ fr7) << 4);
    const char* lB1 = smem + 32768 + (size_t)(wc * 64 + fr) * 128 + (((4 + fq) ^ fr7) << 4);

    KSTAGE(0, 0);
    __syncthreads();

    int cur = 0;
    for (int k0 = 0; k0 < K; k0 += 64) {
        if (k0 + 64 < K) KSTAGE(cur ^ 1, k0 + 64);

#pragma unroll
        for (int ks = 0; ks < 2; ks++) {
            s16x8 af[4], bfr[4];
#pragma unroll
            for (int i = 0; i < 4; i++) {
                af[i]  = *(const s16x8*)((ks ? lA1 : lA0) + cur * 16384 + i * 2048);
                bfr[i] = *(const s16x8*)((ks ? lB1 : lB0) + cur * 16384 + i * 2048);
            }
#pragma unroll
            for (int mi = 0; mi < 4; mi++)
#pragma unroll
                for (int ni = 0; ni < 4; ni++)
                    acc[mi][ni] = __builtin_amdgcn_mfma_f32_16x16x32_bf16(af[mi], bfr[ni], acc[mi][ni], 0, 0, 0);
        }

        __syncthreads();
        cur ^= 1;
    }
#undef KSTAGE

    // epilogue: scatter into swizzled bf16 images (prep pre-zeroed slot 127 & padding)
    const bool isV = (j & 1) != 0;
    u16* img = isV ? J.Vimg : J.Kimg;
    const float scl = isV ? 1.0f : 0.125f;
#pragma unroll
    for (int mi = 0; mi < 4; mi++) {
#pragma unroll
        for (int ni = 0; ni < 4; ni++) {
#pragma unroll
            for (int jj = 0; jj < 4; jj++) {
                int row = m0 + wr * 64 + mi * 16 + fq * 4 + jj;
                if (row < Mj) {
                    int col = n0 + wc * 64 + ni * 16 + fr;
                    int b = row / Lj, kl = row - b * Lj, kg = basej + kl;
                    int h = col >> 6, d = col & 63;
                    size_t bhoff = (size_t)(b * 20 + h) * 16384;
                    int off = isV ? (((d * 256 + (kg >> 3) * 16) ^ ((d & 7) << 4)) + (kg & 7) * 2)
                                  : (((kg * 128 + (d >> 3) * 16) ^ ((kg & 7) << 4)) + (d & 7) * 2);
                    *(u16*)((char*)img + bhoff + off) = f2bf(acc[mi][ni][jj] * scl);
                }
            }
        }
    }
}

// ---------------- MFMA attention (R12-verified: staged K/V via global_load_lds) ----------------
__global__ __launch_bounds__(256) void attn_mfma(
    const u16* __restrict__ q, const u16* __restrict__ Kimg,
    const u16* __restrict__ Vimg, u16* __restrict__ out)
{
    __shared__ char sm[49152];
    char* Qb = sm;
    char* Kb = sm + 16384;
    char* Vb = sm + 32768;

    const int t = threadIdx.x;
    const int lane = t & 63, wid = t >> 6;
    const int lo = lane & 15, hi = lane >> 4;
    const int s0 = blockIdx.x * 128;
    const int bh = blockIdx.y;
    const int b = bh / 20, h = bh - b * 20;
    const size_t rs0 = (size_t)b * 4096 + s0;

    const u16* gk = Kimg + (size_t)bh * 8192;
    const u16* gv = Vimg + (size_t)bh * 8192;
#pragma unroll
    for (int i = 0; i < 4; i++) {
        int ch = t + i * 256;
        __builtin_amdgcn_global_load_lds(AS1(gk + (size_t)ch * 8), AS3(Kb + ch * 16), 16, 0, 0);
        __builtin_amdgcn_global_load_lds(AS1(gv + (size_t)ch * 8), AS3(Vb + ch * 16), 16, 0, 0);
    }
#pragma unroll
    for (int i = 0; i < 4; i++) {
        int ch = t + i * 256;
        int r = ch >> 3, cs = ch & 7;
        u16x8 v = *(const u16x8*)(q + (rs0 + r) * 1280 + h * 64 + cs * 8);
        *(u16x8*)(Qb + ((r * 128 + cs * 16) ^ ((r & 7) << 4))) = v;
    }
    __syncthreads();

    const int m0r = wid * 32;
    s16x8 qf[2][2];
#pragma unroll
    for (int m = 0; m < 2; m++)
#pragma unroll
        for (int kf = 0; kf < 2; kf++) {
            int r = m0r + m * 16 + lo;
            qf[m][kf] = *(const s16x8*)(Qb + ((r * 128 + (kf * 4 + hi) * 16) ^ ((r & 7) << 4)));
        }
    f32x4 sc[2][8];
#pragma unroll
    for (int m = 0; m < 2; m++)
#pragma unroll
        for (int n = 0; n < 8; n++)
            sc[m][n] = (f32x4){0.f, 0.f, 0.f, 0.f};
#pragma unroll
    for (int kf = 0; kf < 2; kf++)
#pragma unroll
        for (int n = 0; n < 8; n++) {
            int r = n * 16 + lo;
            s16x8 kf8 = *(const s16x8*)(Kb + ((r * 128 + (kf * 4 + hi) * 16) ^ ((r & 7) << 4)));
#pragma unroll
            for (int m = 0; m < 2; m++)
                sc[m][n] = __builtin_amdgcn_mfma_f32_16x16x32_bf16(qf[m][kf], kf8, sc[m][n], 0, 0, 0);
        }
    __syncthreads();

    char* Pb = sm + wid * 8192;
#pragma unroll
    for (int m = 0; m < 2; m++) {
#pragma unroll
        for (int j = 0; j < 4; j++) {
            float e[8];
            float s1 = 0.f, s2 = 0.f;
#pragma unroll
            for (int n = 0; n < 8; n++) {
                int col = n * 16 + lo;
                float ev = __expf(sc[m][n][j]);
                e[n] = ev;
                if (col < 87) s1 += ev;
                else if (col < 127) s2 += ev;
            }
#pragma unroll
            for (int d = 1; d < 16; d <<= 1) {
                s1 += __shfl_xor(s1, d);
                s2 += __shfl_xor(s2, d);
            }
            float i1 = 1.f / s1, i2 = 1.f / s2;
            int row = m * 16 + hi * 4 + j;
#pragma unroll
            for (int n = 0; n < 8; n++) {
                int col = n * 16 + lo;
                float w = col < 87 ? i1 : (col < 127 ? i2 : 0.f);
                *(u16*)(Pb + ((row * 256 + col * 2) ^ ((row & 7) << 4))) = f2bf(e[n] * w);
            }
        }
    }
    __syncthreads();

    f32x4 o2[2][4];
#pragma unroll
    for (int m = 0; m < 2; m++)
#pragma unroll
        for (int n = 0; n < 4; n++)
            o2[m][n] = (f32x4){0.f, 0.f, 0.f, 0.f};
#pragma unroll
    for (int kk = 0; kk < 4; kk++) {
        s16x8 pa[2];
#pragma unroll
        for (int m = 0; m < 2; m++) {
            int row = m * 16 + lo;
            pa[m] = *(const s16x8*)(Pb + ((row * 256 + (kk * 4 + hi) * 16) ^ ((row & 7) << 4)));
        }
#pragma unroll
        for (int n = 0; n < 4; n++) {
            int dr = n * 16 + lo;
            s16x8 vf = *(const s16x8*)(Vb + ((dr * 256 + (kk * 4 + hi) * 16) ^ ((dr & 7) << 4)));
#pragma unroll
            for (int m = 0; m < 2; m++)
                o2[m][n] = __builtin_amdgcn_mfma_f32_16x16x32_bf16(pa[m], vf, o2[m][n], 0, 0, 0);
        }
    }

#pragma unroll
    for (int m = 0; m < 2; m++)
#pragma unroll
        for (int n = 0; n < 4; n++)
#pragma unroll
            for (int j = 0; j < 4; j++) {
                size_t row = rs0 + m0r + m * 16 + hi * 4 + j;
                out[row * 1280 + h * 64 + n * 16 + lo] = f2bf(o2[m][n][j]);
            }
}

// ---------------- host ----------------
extern "C" void kernel_launch(void* const* d_in, const int* in_sizes, int n_in,
                              void* d_out, int out_size, void* d_ws, size_t ws_size,
                              hipStream_t stream)
{
    const float* hs  = (const float*)d_in[0];
    const float* ehs = (const float*)d_in[1];
    const float* tbg = (const float*)d_in[2];
    const float* ibg = (const float*)d_in[3];
    const float* Wq  = (const float*)d_in[4];
    const float* Wk  = (const float*)d_in[5];
    const float* Wv  = (const float*)d_in[6];
    const float* Wkt = (const float*)d_in[7];
    const float* Wvt = (const float*)d_in[8];
    const float* Wki = (const float*)d_in[9];
    const float* Wvi = (const float*)d_in[10];
    const float* Wo  = (const float*)d_in[11];
    const float* bo  = (const float*)d_in[12];
    float* out = (float*)d_out;

    const int B = 4, S = 4096, C = 1280, L = 77, Nt = 10, Ni = 40, Dc = 2048, Dt = 768;
    const int M = B * S;   // 16384

    char* p = (char*)d_ws;
    auto alloc = [&](size_t bytes) -> void* {
        void* r = (void*)p;
        p += (bytes + 255) & ~(size_t)255;
        return r;
    };
    u16* hs_b  = (u16*)alloc((size_t)M * C * 2);
    u16* q_b   = (u16*)alloc((size_t)M * C * 2);
    u16* at_b  = (u16*)alloc((size_t)M * C * 2);
    u16* WqT   = (u16*)alloc((size_t)C * C * 2);
    u16* WoT   = (u16*)alloc((size_t)C * C * 2);
    u16* WkT   = (u16*)alloc((size_t)C * Dc * 2);
    u16* WvT   = (u16*)alloc((size_t)C * Dc * 2);
    u16* WkiT  = (u16*)alloc((size_t)C * Dc * 2);
    u16* WviT  = (u16*)alloc((size_t)C * Dc * 2);
    u16* WktT  = (u16*)alloc((size_t)C * Dt * 2);
    u16* WvtT  = (u16*)alloc((size_t)C * Dt * 2);
    u16* ehs_b = (u16*)alloc((size_t)384 * Dc * 2);
    u16* tbg_b = (u16*)alloc((size_t)128 * Dt * 2);
    u16* ibg_b = (u16*)alloc((size_t)256 * Dc * 2);
    u16* Kimg  = (u16*)alloc((size_t)80 * 8192 * 2);   // 1,310,720 B (256-aligned)
    u16* Vimg  = (u16*)alloc((size_t)80 * 8192 * 2);   // contiguous after Kimg

    // ---- prep: casts + weight transposes + image zeroing (1 launch; zeros ordered
    // before gemm_fused's scatter in-stream -> slot 127 & padding deterministic)
    PrepJobs pj;
    pj.cin[0] = hs;  pj.cout[0] = hs_b;
    pj.cin[1] = ehs; pj.cout[1] = ehs_b;
    pj.cin[2] = tbg; pj.cout[2] = tbg_b;
    pj.cin[3] = ibg; pj.cout[3] = ibg_b;
    long c0 = (long)M * C / 4, c1 = (long)B * L * Dc / 4,
         c2 = (long)B * Nt * Dt / 4, c3 = (long)B * Ni * Dc / 4;
    pj.cb[0] = c0; pj.cb[1] = c0 + c1; pj.cb[2] = c0 + c1 + c2;
    const float* wins[8] = {Wq, Wk, Wv, Wkt, Wvt, Wki, Wvi, Wo};
    u16* wouts[8]        = {WqT, WkT, WvT, WktT, WvtT, WkiT, WviT, WoT};
    int wks[8]           = {C, Dc, Dc, Dt, Dt, Dc, Dc, C};
    for (int i = 0; i < 8; i++) { pj.tin[i] = wins[i]; pj.tout[i] = wouts[i]; pj.tK[i] = wks[i]; }
    pj.zbase = (char*)Kimg;   // Kimg+Vimg contiguous: 2,621,440 B = 640 blocks x 4096 B
    prep_kernel<<<21446 + 15360 + 640, 256, 0, stream>>>(pj);

    // ---- fused: KV projections -> images (120 blocks) + q projection (1024 blocks)
    FKV fk;
    const u16* kas[6]  = {ehs_b, ehs_b, tbg_b, tbg_b, ibg_b, ibg_b};
    const u16* kbs[6]  = {WkT, WvT, WktT, WvtT, WkiT, WviT};
    int kks[6]   = {Dc, Dc, Dt, Dt, Dc, Dc};
    int kms[6]   = {B * L, B * L, B * Nt, B * Nt, B * Ni, B * Ni};
    int kls[6]   = {L, L, Nt, Nt, Ni, Ni};
    int kbase[6] = {0, 0, 77, 77, 87, 87};
    for (int i = 0; i < 6; i++) {
        fk.A[i] = kas[i]; fk.Bt[i] = kbs[i];
        fk.K[i] = kks[i]; fk.M[i] = kms[i]; fk.L[i] = kls[i]; fk.base[i] = kbase[i];
    }
    fk.Kimg = Kimg; fk.Vimg = Vimg;
    gemm_fused<<<120 + 1024, 256, 0, stream>>>(hs_b, WqT, q_b, fk);

    // ---- attention (staged K/V, 48KB LDS)
    attn_mfma<<<dim3(S / 128, B * 20), 256, 0, stream>>>(q_b, Kimg, Vimg, at_b);

    // ---- output projection + bias + bf16 residual -> d_out (f32)
    gemm_8p<2><<<1024, 256, 0, stream>>>(at_b, WoT, out, bo, hs_b);
}